// Round 3
// baseline (666.981 us; speedup 1.0000x reference)
//
#include <hip/hip_runtime.h>

// GraphSAGE on MI355X — fp32 I/O (per reference dtypes), split-bf16 MFMA GEMMs.
// Stages: detect edge dtype -> CSR build -> 3x (aggregate + dual GEMM) -> decoder.

#define N_NODES 50000
#define N_EDGES 800000
#define D 128

typedef __bf16 bf16x8 __attribute__((ext_vector_type(8)));
typedef float f32x4 __attribute__((ext_vector_type(4)));

struct bf16pair { bf16x8 hi, lo; };

__device__ inline bf16pair split8(const float* __restrict__ p) {
    bf16pair r;
#pragma unroll
    for (int i = 0; i < 8; ++i) {
        float v = p[i];
        __bf16 h = (__bf16)v;
        r.hi[i] = h;
        r.lo[i] = (__bf16)(v - (float)h);
    }
    return r;
}

// ---------- edge dtype detect: int64 edge values < 2^31 have zero high words ----------
__global__ void detect_kernel(const int* __restrict__ ew, int* __restrict__ flag) {
    __shared__ int s;
    if (threadIdx.x == 0) s = 0;
    __syncthreads();
    int v = 0;
    for (int i = threadIdx.x; i < 1024; i += 256) v |= ew[2 * i + 1];
    if (v) atomicOr(&s, 1);
    __syncthreads();
    if (threadIdx.x == 0) flag[0] = s ? 1 : 2;   // words per element
}

// ---------- CSR build ----------
__global__ void count_kernel(const int* __restrict__ ew, const int* __restrict__ flag,
                             int* __restrict__ cnt) {
    int st = flag[0];
    int e = blockIdx.x * blockDim.x + threadIdx.x;
    if (e < N_EDGES) {
        int d = ew[(size_t)st * (N_EDGES + e)];
        atomicAdd(&cnt[d], 1);
    }
}

__global__ __launch_bounds__(1024) void scan_kernel(const int* __restrict__ cnt,
                                                    int* __restrict__ off,
                                                    int* __restrict__ cursor) {
    __shared__ int sd[1024];
    const int t = threadIdx.x;
    const int CH = (N_NODES + 1023) / 1024;   // 49
    int base = t * CH;
    int s = 0;
    for (int i = 0; i < CH; ++i) {
        int idx = base + i;
        if (idx < N_NODES) s += cnt[idx];
    }
    sd[t] = s;
    __syncthreads();
    for (int d = 1; d < 1024; d <<= 1) {
        int v = (t >= d) ? sd[t - d] : 0;
        __syncthreads();
        sd[t] += v;
        __syncthreads();
    }
    int run = sd[t] - s;   // exclusive prefix of this thread's chunk
    for (int i = 0; i < CH; ++i) {
        int idx = base + i;
        if (idx < N_NODES) {
            off[idx] = run;
            cursor[idx] = run;
            run += cnt[idx];
        }
    }
    if (t == 1023) off[N_NODES] = sd[1023];
}

__global__ void fill_kernel(const int* __restrict__ ew, const int* __restrict__ flag,
                            int* __restrict__ cursor, int* __restrict__ csr) {
    int st = flag[0];
    int e = blockIdx.x * blockDim.x + threadIdx.x;
    if (e < N_EDGES) {
        int d = ew[(size_t)st * (N_EDGES + e)];
        int sidx = ew[(size_t)st * e];
        int pos = atomicAdd(&cursor[d], 1);
        csr[pos] = sidx;
    }
}

// ---------- segment-mean aggregation: one 64-lane wave per node, fp32 ----------
__global__ __launch_bounds__(256) void aggregate_kernel(const float* __restrict__ h,
                                                        const int* __restrict__ off,
                                                        const int* __restrict__ csr,
                                                        float* __restrict__ agg) {
    int gw = blockIdx.x * 4 + (threadIdx.x >> 6);
    int lane = threadIdx.x & 63;
    if (gw >= N_NODES) return;
    int beg = off[gw], end = off[gw + 1];
    float ax = 0.f, ay = 0.f;
    for (int j = beg; j < end; ++j) {
        int s = csr[j];
        float2 v = *reinterpret_cast<const float2*>(h + (size_t)s * D + lane * 2);
        ax += v.x;
        ay += v.y;
    }
    int c = end - beg;
    if (c < 1) c = 1;
    float fc = (float)c;
    float2 o;
    o.x = ax / fc;
    o.y = ay / fc;
    *reinterpret_cast<float2*>(agg + (size_t)gw * D + lane * 2) = o;
}

// ---------- dual GEMM: out = A1 @ W1^T + A2 @ W2^T + b (optional relu), fp32 via split-bf16 ----------
// MFMA 16x16x32 bf16. A-frag: row=lane&15, k=8*(lane>>4)+i. B-frag: col=lane&15, same k.
// D-frag: col=lane&15, row=4*(lane>>4)+r (m89-verified).
__global__ __launch_bounds__(256) void gemm_kernel(const float* __restrict__ A1,
                                                   const float* __restrict__ A2,
                                                   const float* __restrict__ W1,
                                                   const float* __restrict__ W2,
                                                   const float* __restrict__ bias,
                                                   float* __restrict__ out,
                                                   int do_relu) {
    const int lane = threadIdx.x & 63;
    const int wid = threadIdx.x >> 6;   // 4 waves: col ranges of 32
    const int colbase = wid * 32;
    const int lr = lane & 15;
    const int lg = lane >> 4;

    bf16pair B1[2][4], B2[2][4];
    for (int ct = 0; ct < 2; ++ct) {
        int j = colbase + ct * 16 + lr;
        for (int kk = 0; kk < 4; ++kk) {
            int k = kk * 32 + lg * 8;
            B1[ct][kk] = split8(W1 + j * D + k);
            B2[ct][kk] = split8(W2 + j * D + k);
        }
    }
    float bb0 = bias[colbase + lr];
    float bb1 = bias[colbase + 16 + lr];

    const int ntiles = N_NODES / 16;   // 3125
    for (int rt = blockIdx.x; rt < ntiles; rt += gridDim.x) {
        int row = rt * 16 + lr;
        bf16pair Af1[4], Af2[4];
        for (int kk = 0; kk < 4; ++kk) {
            int k = kk * 32 + lg * 8;
            Af1[kk] = split8(A1 + (size_t)row * D + k);
            Af2[kk] = split8(A2 + (size_t)row * D + k);
        }
        for (int ct = 0; ct < 2; ++ct) {
            float bb = ct ? bb1 : bb0;
            f32x4 acc = {bb, bb, bb, bb};
            for (int kk = 0; kk < 4; ++kk) {
                acc = __builtin_amdgcn_mfma_f32_16x16x32_bf16(Af1[kk].hi, B1[ct][kk].hi, acc, 0, 0, 0);
                acc = __builtin_amdgcn_mfma_f32_16x16x32_bf16(Af1[kk].lo, B1[ct][kk].hi, acc, 0, 0, 0);
                acc = __builtin_amdgcn_mfma_f32_16x16x32_bf16(Af1[kk].hi, B1[ct][kk].lo, acc, 0, 0, 0);
                acc = __builtin_amdgcn_mfma_f32_16x16x32_bf16(Af2[kk].hi, B2[ct][kk].hi, acc, 0, 0, 0);
                acc = __builtin_amdgcn_mfma_f32_16x16x32_bf16(Af2[kk].lo, B2[ct][kk].hi, acc, 0, 0, 0);
                acc = __builtin_amdgcn_mfma_f32_16x16x32_bf16(Af2[kk].hi, B2[ct][kk].lo, acc, 0, 0, 0);
            }
            int col = colbase + ct * 16 + lr;
            for (int r = 0; r < 4; ++r) {
                float v = acc[r];
                if (do_relu) v = fmaxf(v, 0.0f);
                int orow = rt * 16 + lg * 4 + r;
                out[(size_t)orow * D + col] = v;
            }
        }
    }
}

// ---------- decoder: out[i][0..1] = h[i] @ Wo^T + bo, wave per node, fp32 ----------
__global__ __launch_bounds__(256) void decoder_kernel(const float* __restrict__ h,
                                                      const float* __restrict__ Wo,
                                                      const float* __restrict__ bo,
                                                      float* __restrict__ out) {
    int lane = threadIdx.x & 63;
    int wid = blockIdx.x * 4 + (threadIdx.x >> 6);
    int nw = gridDim.x * 4;
    float2 w0 = *reinterpret_cast<const float2*>(Wo + lane * 2);
    float2 w1 = *reinterpret_cast<const float2*>(Wo + D + lane * 2);
    float b0 = bo[0], b1 = bo[1];
    for (int i = wid; i < N_NODES; i += nw) {
        float2 v = *reinterpret_cast<const float2*>(h + (size_t)i * D + lane * 2);
        float d0 = v.x * w0.x + v.y * w0.y;
        float d1 = v.x * w1.x + v.y * w1.y;
        for (int m = 1; m < 64; m <<= 1) {
            d0 += __shfl_xor(d0, m, 64);
            d1 += __shfl_xor(d1, m, 64);
        }
        if (lane == 0) {
            float2 o;
            o.x = d0 + b0;
            o.y = d1 + b1;
            *reinterpret_cast<float2*>(out + (size_t)i * 2) = o;
        }
    }
}

extern "C" void kernel_launch(void* const* d_in, const int* in_sizes, int n_in,
                              void* d_out, int out_size, void* d_ws, size_t ws_size,
                              hipStream_t stream) {
    const float* x   = (const float*)d_in[0];
    const int* ew    = (const int*)d_in[1];
    const float* Wl1 = (const float*)d_in[2];
    const float* Wr1 = (const float*)d_in[3];
    const float* b1  = (const float*)d_in[4];
    const float* Wl2 = (const float*)d_in[5];
    const float* Wr2 = (const float*)d_in[6];
    const float* b2  = (const float*)d_in[7];
    const float* Wl3 = (const float*)d_in[8];
    const float* Wr3 = (const float*)d_in[9];
    const float* b3  = (const float*)d_in[10];
    const float* Wo  = (const float*)d_in[11];
    const float* bo  = (const float*)d_in[12];

    char* ws = (char*)d_ws;
    size_t o = 0;
    auto alloc = [&](size_t bytes) {
        char* p = ws + o;
        o += (bytes + 255) & ~(size_t)255;
        return p;
    };
    int* flag   = (int*)alloc(4);
    int* cnt    = (int*)alloc((size_t)N_NODES * 4);
    int* off    = (int*)alloc((size_t)(N_NODES + 1) * 4);
    int* cursor = (int*)alloc((size_t)N_NODES * 4);
    int* csr    = (int*)alloc((size_t)N_EDGES * 4);
    float* agg  = (float*)alloc((size_t)N_NODES * D * 4);
    float* h1   = (float*)alloc((size_t)N_NODES * D * 4);
    float* h2   = (float*)alloc((size_t)N_NODES * D * 4);

    float* outp = (float*)d_out;                 // [N,2]
    float* h3   = outp + (size_t)N_NODES * 2;    // [N,128], tail of d_out

    hipMemsetAsync(cnt, 0, (size_t)N_NODES * 4, stream);
    detect_kernel<<<1, 256, 0, stream>>>(ew, flag);
    count_kernel<<<(N_EDGES + 255) / 256, 256, 0, stream>>>(ew, flag, cnt);
    scan_kernel<<<1, 1024, 0, stream>>>(cnt, off, cursor);
    fill_kernel<<<(N_EDGES + 255) / 256, 256, 0, stream>>>(ew, flag, cursor, csr);

    const int AGG_BLOCKS = (N_NODES + 3) / 4;

    aggregate_kernel<<<AGG_BLOCKS, 256, 0, stream>>>(x, off, csr, agg);
    gemm_kernel<<<512, 256, 0, stream>>>(agg, x, Wl1, Wr1, b1, h1, 1);

    aggregate_kernel<<<AGG_BLOCKS, 256, 0, stream>>>(h1, off, csr, agg);
    gemm_kernel<<<512, 256, 0, stream>>>(agg, h1, Wl2, Wr2, b2, h2, 1);

    aggregate_kernel<<<AGG_BLOCKS, 256, 0, stream>>>(h2, off, csr, agg);
    gemm_kernel<<<512, 256, 0, stream>>>(agg, h2, Wl3, Wr3, b3, h3, 0);

    decoder_kernel<<<2048, 256, 0, stream>>>(h3, Wo, bo, outp);
}

// Round 4
// 479.035 us; speedup vs baseline: 1.3923x; 1.3923x over previous
//
#include <hip/hip_runtime.h>

// GraphSAGE on MI355X — fp32 I/O, split-bf16 MFMA GEMMs, hierarchical CSR scan.
// Stages: detect edge dtype -> CSR build (count / 3-kernel scan / fill)
//         -> 3x (aggregate + dual GEMM) -> decoder.

#define N_NODES 50000
#define N_EDGES 800000
#define D 128
#define NB ((N_NODES + 255) / 256)   // 196 scan blocks

typedef __bf16 bf16x8 __attribute__((ext_vector_type(8)));
typedef float f32x4 __attribute__((ext_vector_type(4)));

struct bf16pair { bf16x8 hi, lo; };

__device__ inline bf16pair split8(const float* __restrict__ p) {
    f32x4 a = *reinterpret_cast<const f32x4*>(p);
    f32x4 b = *reinterpret_cast<const f32x4*>(p + 4);
    bf16pair r;
#pragma unroll
    for (int i = 0; i < 4; ++i) {
        float v = a[i];
        __bf16 h = (__bf16)v;
        r.hi[i] = h;
        r.lo[i] = (__bf16)(v - (float)h);
    }
#pragma unroll
    for (int i = 0; i < 4; ++i) {
        float v = b[i];
        __bf16 h = (__bf16)v;
        r.hi[4 + i] = h;
        r.lo[4 + i] = (__bf16)(v - (float)h);
    }
    return r;
}

// ---------- edge dtype detect: int64 edge values < 2^31 have zero high words ----------
__global__ void detect_kernel(const int* __restrict__ ew, int* __restrict__ flag) {
    __shared__ int s;
    if (threadIdx.x == 0) s = 0;
    __syncthreads();
    int v = 0;
    for (int i = threadIdx.x; i < 1024; i += 256) v |= ew[2 * i + 1];
    if (v) atomicOr(&s, 1);
    __syncthreads();
    if (threadIdx.x == 0) flag[0] = s ? 1 : 2;   // words per element
}

// ---------- CSR build ----------
__global__ void count_kernel(const int* __restrict__ ew, const int* __restrict__ flag,
                             int* __restrict__ cnt) {
    int st = flag[0];
    int e = blockIdx.x * blockDim.x + threadIdx.x;
    if (e < N_EDGES) {
        int d = ew[(size_t)st * (N_EDGES + e)];
        atomicAdd(&cnt[d], 1);
    }
}

// scan1: per-block (256 entries) exclusive prefix into off, block sums into bsum
__global__ __launch_bounds__(256) void scan1_kernel(const int* __restrict__ cnt,
                                                    int* __restrict__ off,
                                                    int* __restrict__ bsum) {
    const int tid = threadIdx.x, lane = tid & 63, wid = tid >> 6;
    const int i = blockIdx.x * 256 + tid;
    int orig = (i < N_NODES) ? cnt[i] : 0;
    int v = orig;
#pragma unroll
    for (int d = 1; d < 64; d <<= 1) {
        int t = __shfl_up(v, d, 64);
        if (lane >= d) v += t;
    }
    __shared__ int ws[4];
    if (lane == 63) ws[wid] = v;
    __syncthreads();
    int base = 0;
    for (int w = 0; w < wid; ++w) base += ws[w];
    v += base;                       // inclusive in-block prefix
    if (i < N_NODES) off[i] = v - orig;   // exclusive (block-local)
    if (tid == 255) bsum[blockIdx.x] = v; // block total
}

// scan2: single block scans NB block sums -> exclusive bases; writes off[N]=total
__global__ __launch_bounds__(256) void scan2_kernel(const int* __restrict__ bsum,
                                                    int* __restrict__ bbase,
                                                    int* __restrict__ off) {
    const int tid = threadIdx.x, lane = tid & 63, wid = tid >> 6;
    int orig = (tid < NB) ? bsum[tid] : 0;
    int v = orig;
#pragma unroll
    for (int d = 1; d < 64; d <<= 1) {
        int t = __shfl_up(v, d, 64);
        if (lane >= d) v += t;
    }
    __shared__ int ws[4];
    if (lane == 63) ws[wid] = v;
    __syncthreads();
    int base = 0;
    for (int w = 0; w < wid; ++w) base += ws[w];
    v += base;
    if (tid < NB) bbase[tid] = v - orig;   // exclusive block base
    if (tid == NB - 1) off[N_NODES] = v;   // total == N_EDGES
}

// scan3: add block base, fill cursor
__global__ __launch_bounds__(256) void scan3_kernel(int* __restrict__ off,
                                                    const int* __restrict__ bbase,
                                                    int* __restrict__ cursor) {
    int i = blockIdx.x * 256 + threadIdx.x;
    if (i < N_NODES) {
        int v = off[i] + bbase[blockIdx.x];
        off[i] = v;
        cursor[i] = v;
    }
}

__global__ void fill_kernel(const int* __restrict__ ew, const int* __restrict__ flag,
                            int* __restrict__ cursor, int* __restrict__ csr) {
    int st = flag[0];
    int e = blockIdx.x * blockDim.x + threadIdx.x;
    if (e < N_EDGES) {
        int d = ew[(size_t)st * (N_EDGES + e)];
        int sidx = ew[(size_t)st * e];
        int pos = atomicAdd(&cursor[d], 1);
        csr[pos] = sidx;
    }
}

// ---------- segment-mean aggregation: one 64-lane wave per node, fp32, x4 unrolled ----------
__global__ __launch_bounds__(256) void aggregate_kernel(const float* __restrict__ h,
                                                        const int* __restrict__ off,
                                                        const int* __restrict__ csr,
                                                        float* __restrict__ agg) {
    int gw = blockIdx.x * 4 + (threadIdx.x >> 6);
    int lane = threadIdx.x & 63;
    if (gw >= N_NODES) return;
    int beg = off[gw], end = off[gw + 1];
    float ax = 0.f, ay = 0.f;
    int j = beg;
    for (; j + 3 < end; j += 4) {
        int s0 = csr[j], s1 = csr[j + 1], s2 = csr[j + 2], s3 = csr[j + 3];
        float2 v0 = *reinterpret_cast<const float2*>(h + (size_t)s0 * D + lane * 2);
        float2 v1 = *reinterpret_cast<const float2*>(h + (size_t)s1 * D + lane * 2);
        float2 v2 = *reinterpret_cast<const float2*>(h + (size_t)s2 * D + lane * 2);
        float2 v3 = *reinterpret_cast<const float2*>(h + (size_t)s3 * D + lane * 2);
        ax += v0.x + v1.x + v2.x + v3.x;
        ay += v0.y + v1.y + v2.y + v3.y;
    }
    for (; j < end; ++j) {
        int s = csr[j];
        float2 v = *reinterpret_cast<const float2*>(h + (size_t)s * D + lane * 2);
        ax += v.x;
        ay += v.y;
    }
    int c = end - beg;
    if (c < 1) c = 1;
    float fc = (float)c;
    float2 o;
    o.x = ax / fc;
    o.y = ay / fc;
    *reinterpret_cast<float2*>(agg + (size_t)gw * D + lane * 2) = o;
}

// ---------- dual GEMM: out = A1 @ W1^T + A2 @ W2^T + b (optional relu), fp32 via split-bf16 ----------
// MFMA 16x16x32 bf16. A-frag: row=lane&15, k=8*(lane>>4)+i. B-frag: col=lane&15, same k.
// D-frag: col=lane&15, row=4*(lane>>4)+r (m89-verified).
__global__ __launch_bounds__(256) void gemm_kernel(const float* __restrict__ A1,
                                                   const float* __restrict__ A2,
                                                   const float* __restrict__ W1,
                                                   const float* __restrict__ W2,
                                                   const float* __restrict__ bias,
                                                   float* __restrict__ out,
                                                   int do_relu) {
    const int lane = threadIdx.x & 63;
    const int wid = threadIdx.x >> 6;   // 4 waves: col ranges of 32
    const int colbase = wid * 32;
    const int lr = lane & 15;
    const int lg = lane >> 4;

    bf16pair B1[2][4], B2[2][4];
    for (int ct = 0; ct < 2; ++ct) {
        int j = colbase + ct * 16 + lr;
        for (int kk = 0; kk < 4; ++kk) {
            int k = kk * 32 + lg * 8;
            B1[ct][kk] = split8(W1 + j * D + k);
            B2[ct][kk] = split8(W2 + j * D + k);
        }
    }
    float bb0 = bias[colbase + lr];
    float bb1 = bias[colbase + 16 + lr];

    const int ntiles = N_NODES / 16;   // 3125
    for (int rt = blockIdx.x; rt < ntiles; rt += gridDim.x) {
        int row = rt * 16 + lr;
        bf16pair Af1[4], Af2[4];
        for (int kk = 0; kk < 4; ++kk) {
            int k = kk * 32 + lg * 8;
            Af1[kk] = split8(A1 + (size_t)row * D + k);
            Af2[kk] = split8(A2 + (size_t)row * D + k);
        }
        for (int ct = 0; ct < 2; ++ct) {
            float bb = ct ? bb1 : bb0;
            f32x4 acc = {bb, bb, bb, bb};
            for (int kk = 0; kk < 4; ++kk) {
                acc = __builtin_amdgcn_mfma_f32_16x16x32_bf16(Af1[kk].hi, B1[ct][kk].hi, acc, 0, 0, 0);
                acc = __builtin_amdgcn_mfma_f32_16x16x32_bf16(Af1[kk].lo, B1[ct][kk].hi, acc, 0, 0, 0);
                acc = __builtin_amdgcn_mfma_f32_16x16x32_bf16(Af1[kk].hi, B1[ct][kk].lo, acc, 0, 0, 0);
                acc = __builtin_amdgcn_mfma_f32_16x16x32_bf16(Af2[kk].hi, B2[ct][kk].hi, acc, 0, 0, 0);
                acc = __builtin_amdgcn_mfma_f32_16x16x32_bf16(Af2[kk].lo, B2[ct][kk].hi, acc, 0, 0, 0);
                acc = __builtin_amdgcn_mfma_f32_16x16x32_bf16(Af2[kk].hi, B2[ct][kk].lo, acc, 0, 0, 0);
            }
            int col = colbase + ct * 16 + lr;
            for (int r = 0; r < 4; ++r) {
                float v = acc[r];
                if (do_relu) v = fmaxf(v, 0.0f);
                int orow = rt * 16 + lg * 4 + r;
                out[(size_t)orow * D + col] = v;
            }
        }
    }
}

// ---------- decoder: out[i][0..1] = h[i] @ Wo^T + bo, wave per node, fp32 ----------
__global__ __launch_bounds__(256) void decoder_kernel(const float* __restrict__ h,
                                                      const float* __restrict__ Wo,
                                                      const float* __restrict__ bo,
                                                      float* __restrict__ out) {
    int lane = threadIdx.x & 63;
    int wid = blockIdx.x * 4 + (threadIdx.x >> 6);
    int nw = gridDim.x * 4;
    float2 w0 = *reinterpret_cast<const float2*>(Wo + lane * 2);
    float2 w1 = *reinterpret_cast<const float2*>(Wo + D + lane * 2);
    float b0 = bo[0], b1 = bo[1];
    for (int i = wid; i < N_NODES; i += nw) {
        float2 v = *reinterpret_cast<const float2*>(h + (size_t)i * D + lane * 2);
        float d0 = v.x * w0.x + v.y * w0.y;
        float d1 = v.x * w1.x + v.y * w1.y;
        for (int m = 1; m < 64; m <<= 1) {
            d0 += __shfl_xor(d0, m, 64);
            d1 += __shfl_xor(d1, m, 64);
        }
        if (lane == 0) {
            float2 o;
            o.x = d0 + b0;
            o.y = d1 + b1;
            *reinterpret_cast<float2*>(out + (size_t)i * 2) = o;
        }
    }
}

extern "C" void kernel_launch(void* const* d_in, const int* in_sizes, int n_in,
                              void* d_out, int out_size, void* d_ws, size_t ws_size,
                              hipStream_t stream) {
    const float* x   = (const float*)d_in[0];
    const int* ew    = (const int*)d_in[1];
    const float* Wl1 = (const float*)d_in[2];
    const float* Wr1 = (const float*)d_in[3];
    const float* b1  = (const float*)d_in[4];
    const float* Wl2 = (const float*)d_in[5];
    const float* Wr2 = (const float*)d_in[6];
    const float* b2  = (const float*)d_in[7];
    const float* Wl3 = (const float*)d_in[8];
    const float* Wr3 = (const float*)d_in[9];
    const float* b3  = (const float*)d_in[10];
    const float* Wo  = (const float*)d_in[11];
    const float* bo  = (const float*)d_in[12];

    char* ws = (char*)d_ws;
    size_t o = 0;
    auto alloc = [&](size_t bytes) {
        char* p = ws + o;
        o += (bytes + 255) & ~(size_t)255;
        return p;
    };
    int* flag   = (int*)alloc(4);
    int* cnt    = (int*)alloc((size_t)N_NODES * 4);
    int* off    = (int*)alloc((size_t)(N_NODES + 1) * 4);
    int* cursor = (int*)alloc((size_t)N_NODES * 4);
    int* csr    = (int*)alloc((size_t)N_EDGES * 4);
    int* bsum   = (int*)alloc((size_t)NB * 4);
    int* bbase  = (int*)alloc((size_t)NB * 4);
    float* agg  = (float*)alloc((size_t)N_NODES * D * 4);
    float* h1   = (float*)alloc((size_t)N_NODES * D * 4);
    float* h2   = (float*)alloc((size_t)N_NODES * D * 4);

    float* outp = (float*)d_out;                 // [N,2]
    float* h3   = outp + (size_t)N_NODES * 2;    // [N,128], tail of d_out

    hipMemsetAsync(cnt, 0, (size_t)N_NODES * 4, stream);
    detect_kernel<<<1, 256, 0, stream>>>(ew, flag);
    count_kernel<<<(N_EDGES + 255) / 256, 256, 0, stream>>>(ew, flag, cnt);
    scan1_kernel<<<NB, 256, 0, stream>>>(cnt, off, bsum);
    scan2_kernel<<<1, 256, 0, stream>>>(bsum, bbase, off);
    scan3_kernel<<<NB, 256, 0, stream>>>(off, bbase, cursor);
    fill_kernel<<<(N_EDGES + 255) / 256, 256, 0, stream>>>(ew, flag, cursor, csr);

    const int AGG_BLOCKS = (N_NODES + 3) / 4;

    aggregate_kernel<<<AGG_BLOCKS, 256, 0, stream>>>(x, off, csr, agg);
    gemm_kernel<<<512, 256, 0, stream>>>(agg, x, Wl1, Wr1, b1, h1, 1);

    aggregate_kernel<<<AGG_BLOCKS, 256, 0, stream>>>(h1, off, csr, agg);
    gemm_kernel<<<512, 256, 0, stream>>>(agg, h1, Wl2, Wr2, b2, h2, 1);

    aggregate_kernel<<<AGG_BLOCKS, 256, 0, stream>>>(h2, off, csr, agg);
    gemm_kernel<<<512, 256, 0, stream>>>(agg, h2, Wl3, Wr3, b3, h3, 0);

    decoder_kernel<<<2048, 256, 0, stream>>>(h3, Wo, bo, outp);
}